// Round 5
// baseline (245.417 us; speedup 1.0000x reference)
//
#include <hip/hip_runtime.h>
#include <hip/hip_bf16.h>
#include <math.h>

// Problem constants (fixed by the reference).
#define BB    4
#define CC    256
#define CHN   128
#define NN    4096

typedef short short8 __attribute__((ext_vector_type(8)));   // 8 bf16 (MFMA A/B frag)
typedef float f32x4  __attribute__((ext_vector_type(4)));   // MFMA C/D frag
typedef unsigned short u16;
typedef u16  us4 __attribute__((ext_vector_type(4)));

#define MFMA16(a, b, c) __builtin_amdgcn_mfma_f32_16x16x32_bf16((a), (b), (c), 0, 0, 0)
#define LOG2E 1.4426950408889634f

#if __has_builtin(__builtin_amdgcn_exp2f)
#define EXP2F(x) __builtin_amdgcn_exp2f(x)
#else
#define EXP2F(x) exp2f(x)
#endif
#if __has_builtin(__builtin_amdgcn_logf)
#define LOG2F(x) __builtin_amdgcn_logf(x)   // v_log_f32 IS log2
#else
#define LOG2F(x) log2f(x)
#endif

static __device__ __forceinline__ u16 f2bf(float f) {           // RNE float->bf16
    union { float f; unsigned u; } v; v.f = f;
    unsigned r = v.u + 0x7FFFu + ((v.u >> 16) & 1u);
    return (u16)(r >> 16);
}
// packed f32x2 -> bf16x2 (v_cvt_pk_bf16_f32 on gfx950)
static __device__ __forceinline__ unsigned pkbf(float a, float b) {
    __hip_bfloat162 h = __float22bfloat162_rn(make_float2(a, b));
    return *reinterpret_cast<unsigned*>(&h);
}
// XOR-swizzled LDS address (u16 units), [row][128] bf16 tiles, 16B chunks.
static __device__ __forceinline__ int sw128(int row, int u) {
    return row * 128 + ((u ^ (row & 7)) << 3);
}
// XOR-swizzled LDS address (u16 units), [row][64] bf16 tiles, 16B chunks.
static __device__ __forceinline__ int sw64(int row, int u) {
    return row * 64 + ((u ^ (row & 7)) << 3);
}

// ---------------------------------------------------------------------------
// K0: convert 4 weight matrices fp32->bf16. wall = [tw|pw|gw|Ww], 32768 each.
// theta weights pre-scaled by log2(e): scores land in exp2 domain.
// ---------------------------------------------------------------------------
__global__ __launch_bounds__(256) void k_cvtw(
    const float* __restrict__ tw, const float* __restrict__ pw,
    const float* __restrict__ gw, const float* __restrict__ Ww,
    u16* __restrict__ wall)
{
    int idx = (blockIdx.x * 256 + threadIdx.x) * 4;   // 0 .. 131071
    const float* s = (idx < 32768) ? tw
                   : (idx < 65536) ? pw
                   : (idx < 98304) ? gw : Ww;
    float sc = (idx < 32768) ? LOG2E : 1.0f;
    float4 v = *(const float4*)(s + (idx & 32767));
    us4 r = { f2bf(v.x * sc), f2bf(v.y * sc), f2bf(v.z * sc), f2bf(v.w * sc) };
    *(us4*)(wall + idx) = r;
}

// ---------------------------------------------------------------------------
// K1: MFMA projections, 512 threads. A = weights (global k-major frags),
// B = x^T tile in LDS (staged once, frags hoisted, reused 3x).
//  tht/pht: [b][n][c] bf16 k-major; gg: [b][c][n] bf16 (k-major in j).
// ---------------------------------------------------------------------------
__global__ __launch_bounds__(512) void k_proj(
    const float* __restrict__ x, const u16* __restrict__ wall,
    const float* __restrict__ tb, const float* __restrict__ pb,
    const float* __restrict__ gbias,
    u16* __restrict__ tht, u16* __restrict__ pht, u16* __restrict__ gg)
{
    __shared__ u16 xs[64 * 264];    // x^T tile [n][c], pitch 264
    __shared__ u16 gbuf[128 * 68];  // g transpose bounce [o][n]
    const int tid = threadIdx.x;
    const int n0  = blockIdx.x * 64;
    const int b   = blockIdx.y;
    const int ln  = tid & 15, q = (tid >> 4) & 3, wid = tid >> 6;
    const int ow  = wid & 1, nw = wid >> 1;

    for (int p = 0; p < 8; ++p) {
        int id = p * 512 + tid;          // 4096 chunks: c(256) x n4(16)
        int c = id >> 4, n4 = (id & 15) * 4;
        float4 xv = *(const float4*)(x + ((size_t)b * CC + c) * NN + n0 + n4);
        xs[(n4 + 0) * 264 + c] = f2bf(xv.x);
        xs[(n4 + 1) * 264 + c] = f2bf(xv.y);
        xs[(n4 + 2) * 264 + c] = f2bf(xv.z);
        xs[(n4 + 3) * 264 + c] = f2bf(xv.w);
    }
    __syncthreads();

    short8 bfr[8];
    #pragma unroll
    for (int ks = 0; ks < 8; ++ks)
        bfr[ks] = *(const short8*)(&xs[(nw * 16 + ln) * 264 + ks * 32 + q * 8]);

    for (int pr = 0; pr < 3; ++pr) {
        const u16* wsrc = wall + pr * 32768;
        f32x4 acc[4];
        #pragma unroll
        for (int oo = 0; oo < 4; ++oo) acc[oo] = (f32x4){0.f, 0.f, 0.f, 0.f};
        for (int ks = 0; ks < 8; ++ks) {
            short8 a[4];
            #pragma unroll
            for (int oo = 0; oo < 4; ++oo)
                a[oo] = *(const short8*)(wsrc + (size_t)(ow*64 + oo*16 + ln) * 256 + ks*32 + q*8);
            #pragma unroll
            for (int oo = 0; oo < 4; ++oo)
                acc[oo] = MFMA16(a[oo], bfr[ks], acc[oo]);
        }
        const float* bias = (pr == 0) ? tb : (pr == 1 ? pb : gbias);
        const float bsc = (pr == 0) ? LOG2E : 1.0f;
        if (pr < 2) {
            u16* dst = (pr == 0) ? tht : pht;
            const int n = n0 + nw * 16 + ln;
            #pragma unroll
            for (int oo = 0; oo < 4; ++oo) {
                int o = ow * 64 + oo * 16 + q * 4;
                float4 bv = *(const float4*)(bias + o);
                f32x4 v = acc[oo];
                uint2 r = { pkbf(v.x + bv.x * bsc, v.y + bv.y * bsc),
                            pkbf(v.z + bv.z * bsc, v.w + bv.w * bsc) };
                *(uint2*)(dst + ((size_t)b * NN + n) * CHN + o) = r;
            }
        } else {
            const int nl = nw * 16 + ln;
            #pragma unroll
            for (int oo = 0; oo < 4; ++oo) {
                int o = ow * 64 + oo * 16 + q * 4;
                float4 bv = *(const float4*)(bias + o);
                f32x4 v = acc[oo];
                gbuf[(o + 0) * 68 + nl] = f2bf(v.x + bv.x);
                gbuf[(o + 1) * 68 + nl] = f2bf(v.y + bv.y);
                gbuf[(o + 2) * 68 + nl] = f2bf(v.z + bv.z);
                gbuf[(o + 3) * 68 + nl] = f2bf(v.w + bv.w);
            }
            __syncthreads();
            for (int p = 0; p < 4; ++p) {
                int id = p * 512 + tid;      // 2048 chunks: c(128) x n4(16)
                int c = id >> 4, n4 = (id & 15) * 4;
                us4 r = *(const us4*)(&gbuf[c * 68 + n4]);
                *(us4*)(gg + ((size_t)b * CHN + c) * NN + n0 + n4) = r;
            }
        }
    }
}

// ---------------------------------------------------------------------------
// K2: partial Z[b][j] += sum_i exp2(S2_ji), fp32 atomicAdd.
// 256 threads. theta j-128 frags REGISTER-resident (global, once).
// phi i-chunk 512, 8 steps of 64, DOUBLE-BUFFERED LDS (1 barrier/step).
// LDS 32 KB -> 3-4 blocks/CU. Grid (32, 8, B) = 1024 blocks.
// Waves: 2 (j-half 64) x 2 (i-half 32/step).
// ---------------------------------------------------------------------------
__global__ __launch_bounds__(256) void k_rowsum(
    const u16* __restrict__ tht, const u16* __restrict__ pht,
    float* __restrict__ Z)
{
    __shared__ u16 ph_s[2][64 * 128];
    const int tid = threadIdx.x;
    const int j0  = blockIdx.x * 128;
    const int i00 = blockIdx.y * 512;
    const int b   = blockIdx.z;
    const int ln  = tid & 15, q = (tid >> 4) & 3, wid = tid >> 6;
    const int jw  = wid & 1, iw = wid >> 1;
    const u16* thb = tht + (size_t)b * NN * CHN;
    const u16* phb = pht + (size_t)b * NN * CHN;

    // theta fragments: registers, loaded once
    short8 ar[4][4];
    #pragma unroll
    for (int jj = 0; jj < 4; ++jj)
        #pragma unroll
        for (int ks = 0; ks < 4; ++ks)
            ar[jj][ks] = *(const short8*)(thb + (size_t)(j0 + jw*64 + jj*16 + ln) * CHN + ks*32 + q*8);

    // stage step 0
    for (int p = 0; p < 4; ++p) {
        int id = p * 256 + tid;
        int row = id >> 4, u = id & 15;
        short8 v = *(const short8*)(phb + (size_t)(i00 + row) * CHN + u * 8);
        *(short8*)(&ph_s[0][sw128(row, u)]) = v;
    }

    float zp[4][4];
    #pragma unroll
    for (int jj = 0; jj < 4; ++jj)
        #pragma unroll
        for (int r = 0; r < 4; ++r) zp[jj][r] = 0.f;

    for (int is = 0; is < 8; ++is) {
        __syncthreads();   // ph_s[is&1] staged; ph_s[(is+1)&1] free
        if (is < 7) {
            for (int p = 0; p < 4; ++p) {
                int id = p * 256 + tid;
                int row = id >> 4, u = id & 15;
                short8 v = *(const short8*)(phb + (size_t)(i00 + (is+1)*64 + row) * CHN + u * 8);
                *(short8*)(&ph_s[(is + 1) & 1][sw128(row, u)]) = v;
            }
        }
        const u16* cur = ph_s[is & 1];

        f32x4 s[4][2];
        #pragma unroll
        for (int jj = 0; jj < 4; ++jj)
            #pragma unroll
            for (int ii = 0; ii < 2; ++ii) s[jj][ii] = (f32x4){0.f, 0.f, 0.f, 0.f};
        #pragma unroll
        for (int ks = 0; ks < 4; ++ks) {
            short8 bb[2];
            #pragma unroll
            for (int ii = 0; ii < 2; ++ii)
                bb[ii] = *(const short8*)(&cur[sw128(iw*32 + ii*16 + ln, ks*4 + q)]);
            #pragma unroll
            for (int jj = 0; jj < 4; ++jj) {
                s[jj][0] = MFMA16(ar[jj][ks], bb[0], s[jj][0]);
                s[jj][1] = MFMA16(ar[jj][ks], bb[1], s[jj][1]);
            }
        }
        #pragma unroll
        for (int jj = 0; jj < 4; ++jj)
            #pragma unroll
            for (int ii = 0; ii < 2; ++ii) {
                f32x4 v = s[jj][ii];
                zp[jj][0] += EXP2F(v.x);
                zp[jj][1] += EXP2F(v.y);
                zp[jj][2] += EXP2F(v.z);
                zp[jj][3] += EXP2F(v.w);
            }
    }

    // reduce across the 16 i-lanes of each quad, then atomicAdd partial Z
    #pragma unroll
    for (int jj = 0; jj < 4; ++jj)
        #pragma unroll
        for (int r = 0; r < 4; ++r) {
            float v = zp[jj][r];
            v += __shfl_xor(v, 1);
            v += __shfl_xor(v, 2);
            v += __shfl_xor(v, 4);
            v += __shfl_xor(v, 8);
            if (ln == 0)
                atomicAdd(&Z[(size_t)b * NN + j0 + jw*64 + jj*16 + q*4 + r], v);
        }
}

// ---------------------------------------------------------------------------
// K3: fused attention, 256 threads, i-tile 64 (phi frags REGISTER-resident,
// loaded from global once), j-quarter 1024 = 16 steps of 64.
//  phase1: S2 = th'_j.ph_i, C-init = -log2(Z_j) -> E = exp2(S2-L) bf16 in LDS
//  phase2: innerT[i][c] += E[i][j] * g[c][j]
// LDS: th 16K + g 16K + E 8K = 40 KB -> 4 blocks/CU (16 waves, 4/SIMD).
// Grid (64, 4, B) = 1024 blocks.
// Phase1 waves: j-16 each (wid). Phase2 waves: c-32 each (wid).
// ---------------------------------------------------------------------------
__global__ __launch_bounds__(256) void k_attn(
    const u16* __restrict__ tht, const u16* __restrict__ pht,
    const u16* __restrict__ gg, const float* __restrict__ Z,
    u16* __restrict__ innerT)
{
    __shared__ u16 th_s[64 * 128];   // [j][c]
    __shared__ u16 g_s [128 * 64];   // [c][j]
    __shared__ u16 E_s [64 * 64];    // [i][j]
    const int tid = threadIdx.x;
    const int i0  = blockIdx.x * 64;
    const int jq  = blockIdx.y;
    const int b   = blockIdx.z;
    const int ln  = tid & 15, q = (tid >> 4) & 3, wid = tid >> 6;

    const u16*  thb = tht + (size_t)b * NN * CHN;
    const u16*  ggb = gg  + (size_t)b * CHN * NN;
    const float* Zb = Z   + (size_t)b * NN;

    // phi fragments for the whole i-tile: registers, loaded once (all waves same)
    short8 phr[4][4];
    #pragma unroll
    for (int ii = 0; ii < 4; ++ii)
        #pragma unroll
        for (int ks = 0; ks < 4; ++ks)
            phr[ii][ks] = *(const short8*)(pht + ((size_t)b * NN + i0 + ii*16 + ln) * CHN + ks*32 + q*8);

    f32x4 pacc[2][4];   // [cc][ii]
    #pragma unroll
    for (int cc = 0; cc < 2; ++cc)
        #pragma unroll
        for (int ii = 0; ii < 4; ++ii) pacc[cc][ii] = (f32x4){0.f, 0.f, 0.f, 0.f};

    for (int js = 0; js < 16; ++js) {
        const int j0 = jq * 1024 + js * 64;
        __syncthreads();   // prev step's phase1/2 done with th/g/E
        // stage theta [64 j][128 c]
        for (int p = 0; p < 4; ++p) {
            int id = p * 256 + tid;
            int row = id >> 4, u = id & 15;
            short8 v = *(const short8*)(thb + (size_t)(j0 + row) * CHN + u * 8);
            *(short8*)(&th_s[sw128(row, u)]) = v;
        }
        // stage g [128 c][64 j]
        for (int p = 0; p < 4; ++p) {
            int id = p * 256 + tid;
            int row = id >> 3, u = id & 7;
            short8 v = *(const short8*)(ggb + (size_t)row * NN + j0 + u * 8);
            *(short8*)(&g_s[sw64(row, u)]) = v;
        }
        __syncthreads();

        // ---- phase 1: wave owns j-16 (rows wid*16..), all 64 i
        {
            const int jl = wid * 16 + q * 4;
            float4 Zv = *(const float4*)(Zb + j0 + jl);
            f32x4 cinit = { -LOG2F(Zv.x), -LOG2F(Zv.y), -LOG2F(Zv.z), -LOG2F(Zv.w) };
            f32x4 s0 = cinit, s1 = cinit, s2 = cinit, s3 = cinit;
            #pragma unroll
            for (int ks = 0; ks < 4; ++ks) {
                short8 a = *(const short8*)(&th_s[sw128(wid*16 + ln, ks*4 + q)]);
                s0 = MFMA16(a, phr[0][ks], s0);
                s1 = MFMA16(a, phr[1][ks], s1);
                s2 = MFMA16(a, phr[2][ks], s2);
                s3 = MFMA16(a, phr[3][ks], s3);
            }
            const int u = jl >> 3, off = jl & 7;
            f32x4 sv[4] = { s0, s1, s2, s3 };
            #pragma unroll
            for (int ii = 0; ii < 4; ++ii) {
                int ri = ii*16 + ln;
                f32x4 v = sv[ii];
                uint2 e = { pkbf(EXP2F(v.x), EXP2F(v.y)),
                            pkbf(EXP2F(v.z), EXP2F(v.w)) };
                *(uint2*)(&E_s[ri*64 + ((u ^ (ri & 7)) << 3) + off]) = e;
            }
        }
        __syncthreads();

        // ---- phase 2: wave owns c-32 (rows wid*32..), all 64 i, K = 64 j
        #pragma unroll
        for (int ks = 0; ks < 2; ++ks) {
            short8 be[4];
            #pragma unroll
            for (int ii = 0; ii < 4; ++ii)
                be[ii] = *(const short8*)(&E_s[sw64(ii*16 + ln, ks*4 + q)]);
            #pragma unroll
            for (int cc = 0; cc < 2; ++cc) {
                short8 ag = *(const short8*)(&g_s[sw64(wid*32 + cc*16 + ln, ks*4 + q)]);
                pacc[cc][0] = MFMA16(ag, be[0], pacc[cc][0]);
                pacc[cc][1] = MFMA16(ag, be[1], pacc[cc][1]);
                pacc[cc][2] = MFMA16(ag, be[2], pacc[cc][2]);
                pacc[cc][3] = MFMA16(ag, be[3], pacc[cc][3]);
            }
        }
    }

    // epilogue: D col=i (lane), rows = 4 consecutive c -> 8B stores into [i][c]
    u16* dst = innerT + ((size_t)jq * BB + b) * (size_t)NN * CHN;
    #pragma unroll
    for (int cc = 0; cc < 2; ++cc)
        #pragma unroll
        for (int ii = 0; ii < 4; ++ii) {
            int i = i0 + ii*16 + ln;
            int c = wid*32 + cc*16 + q*4;
            f32x4 v = pacc[cc][ii];
            uint2 r = { pkbf(v.x, v.y), pkbf(v.z, v.w) };
            *(uint2*)(dst + (size_t)i * CHN + c) = r;
        }
}

// ---------------------------------------------------------------------------
// K4: out[b][o][n] = Wb[o] + x[b][o][n] + sum_c Ww[o][c]*(sum_q innerT_q)[n][c]
// Pure-MFMA, quarter partials summed in the fp32 accumulator.
// ---------------------------------------------------------------------------
__global__ __launch_bounds__(512) void k_final(
    const u16* __restrict__ innerT, const float* __restrict__ x,
    const u16* __restrict__ Wwbf, const float* __restrict__ Wb,
    float* __restrict__ out)
{
    const int tid = threadIdx.x;
    const int n0  = blockIdx.x * 64;
    const int b   = blockIdx.y;
    const int ln  = tid & 15, q = (tid >> 4) & 3, wid = tid >> 6;

    f32x4 acc[4][2];
    #pragma unroll
    for (int nn = 0; nn < 4; ++nn)
        #pragma unroll
        for (int oo = 0; oo < 2; ++oo) acc[nn][oo] = (f32x4){0.f, 0.f, 0.f, 0.f};

    for (int jq = 0; jq < 4; ++jq) {
        const u16* src = innerT + ((size_t)jq * BB + b) * (size_t)NN * CHN;
        for (int ks = 0; ks < 4; ++ks) {
            short8 a[4], bw[2];
            #pragma unroll
            for (int nn = 0; nn < 4; ++nn)
                a[nn] = *(const short8*)(src + (size_t)(n0 + nn*16 + ln) * CHN + ks*32 + q*8);
            #pragma unroll
            for (int oo = 0; oo < 2; ++oo)
                bw[oo] = *(const short8*)(Wwbf + (size_t)(wid*32 + oo*16 + ln) * CHN + ks*32 + q*8);
            #pragma unroll
            for (int nn = 0; nn < 4; ++nn)
                #pragma unroll
                for (int oo = 0; oo < 2; ++oo)
                    acc[nn][oo] = MFMA16(a[nn], bw[oo], acc[nn][oo]);
        }
    }
    #pragma unroll
    for (int nn = 0; nn < 4; ++nn)
        #pragma unroll
        for (int oo = 0; oo < 2; ++oo) {
            int o = wid*32 + oo*16 + ln;
            int n = n0 + nn*16 + q*4;
            size_t idx = ((size_t)b * CC + o) * NN + n;
            float4 xv = *(const float4*)(x + idx);
            float wb = Wb[o];
            f32x4 v = acc[nn][oo];
            f32x4 r = { v.x + wb + xv.x, v.y + wb + xv.y,
                        v.z + wb + xv.z, v.w + wb + xv.w };
            *(f32x4*)(out + idx) = r;
        }
}

// ---------------------------------------------------------------------------
extern "C" void kernel_launch(void* const* d_in, const int* in_sizes, int n_in,
                              void* d_out, int out_size, void* d_ws, size_t ws_size,
                              hipStream_t stream)
{
    const float* x  = (const float*)d_in[0];
    const float* tw = (const float*)d_in[1];
    const float* tb = (const float*)d_in[2];
    const float* pw = (const float*)d_in[3];
    const float* pb = (const float*)d_in[4];
    const float* gw = (const float*)d_in[5];
    const float* gb = (const float*)d_in[6];
    const float* Ww = (const float*)d_in[7];
    const float* Wb = (const float*)d_in[8];
    float* out = (float*)d_out;

    // Workspace (~29 MB): tht|pht|gg (4MB ea bf16) | wall (256KB) |
    // Z (64KB fp32, memset to 0) | innerT 4 quarters x 4MB bf16.
    char* p = (char*)d_ws;
    const size_t proj_u16 = (size_t)BB * NN * CHN;   // 2,097,152
    u16*   tht    = (u16*)p;   p += proj_u16 * 2;
    u16*   pht    = (u16*)p;   p += proj_u16 * 2;
    u16*   gg     = (u16*)p;   p += proj_u16 * 2;
    u16*   wall   = (u16*)p;   p += (size_t)131072 * 2;
    float* Z      = (float*)p; p += (size_t)BB * NN * 4;
    u16*   innerT = (u16*)p;

    hipMemsetAsync(Z, 0, (size_t)BB * NN * sizeof(float), stream);
    k_cvtw  <<<128, 256, 0, stream>>>(tw, pw, gw, Ww, wall);
    k_proj  <<<dim3(64, BB), 512, 0, stream>>>(x, wall, tb, pb, gb, tht, pht, gg);
    k_rowsum<<<dim3(32, 8, BB), 256, 0, stream>>>(tht, pht, Z);
    k_attn  <<<dim3(64, 4, BB), 256, 0, stream>>>(tht, pht, gg, Z, innerT);
    k_final <<<dim3(64, BB), 512, 0, stream>>>(innerT, x, wall + 98304, Wb, out);
}

// Round 6
// 196.440 us; speedup vs baseline: 1.2493x; 1.2493x over previous
//
#include <hip/hip_runtime.h>
#include <hip/hip_bf16.h>
#include <math.h>

// Problem constants (fixed by the reference).
#define BB    4
#define CC    256
#define CHN   128
#define NN    4096

typedef short short8 __attribute__((ext_vector_type(8)));    // 8 bf16 (MFMA A/B frag)
typedef float f32x4  __attribute__((ext_vector_type(4)));    // 16x16 C/D frag
typedef float f32x16 __attribute__((ext_vector_type(16)));   // 32x32 C/D frag
typedef unsigned short u16;
typedef u16  us4 __attribute__((ext_vector_type(4)));

#define MFMA16(a, b, c) __builtin_amdgcn_mfma_f32_16x16x32_bf16((a), (b), (c), 0, 0, 0)
#define MFMA32(a, b, c) __builtin_amdgcn_mfma_f32_32x32x16_bf16((a), (b), (c), 0, 0, 0)
#define LOG2E 1.4426950408889634f

#if __has_builtin(__builtin_amdgcn_exp2f)
#define EXP2F(x) __builtin_amdgcn_exp2f(x)
#else
#define EXP2F(x) exp2f(x)
#endif
#if __has_builtin(__builtin_amdgcn_logf)
#define LOG2F(x) __builtin_amdgcn_logf(x)   // v_log_f32 IS log2
#else
#define LOG2F(x) log2f(x)
#endif

static __device__ __forceinline__ u16 f2bf(float f) {           // RNE float->bf16
    union { float f; unsigned u; } v; v.f = f;
    unsigned r = v.u + 0x7FFFu + ((v.u >> 16) & 1u);
    return (u16)(r >> 16);
}
// packed f32x2 -> bf16x2 (v_cvt_pk_bf16_f32 on gfx950)
static __device__ __forceinline__ unsigned pkbf(float a, float b) {
    __hip_bfloat162 h = __float22bfloat162_rn(make_float2(a, b));
    return *reinterpret_cast<unsigned*>(&h);
}
// XOR-swizzled LDS address (u16 units), [row][128] bf16 tiles, 16B chunks.
// Element (row, k) lives at row*128 + (((k>>3) ^ (row&7))<<3) + (k&7).
static __device__ __forceinline__ int sw128(int row, int u) {
    return row * 128 + ((u ^ (row & 7)) << 3);
}

// ---------------------------------------------------------------------------
// K0: convert 4 weight matrices fp32->bf16. wall = [tw|pw|gw|Ww], 32768 each.
// theta weights pre-scaled by log2(e): scores land in exp2 domain.
// ---------------------------------------------------------------------------
__global__ __launch_bounds__(256) void k_cvtw(
    const float* __restrict__ tw, const float* __restrict__ pw,
    const float* __restrict__ gw, const float* __restrict__ Ww,
    u16* __restrict__ wall)
{
    int idx = (blockIdx.x * 256 + threadIdx.x) * 4;   // 0 .. 131071
    const float* s = (idx < 32768) ? tw
                   : (idx < 65536) ? pw
                   : (idx < 98304) ? gw : Ww;
    float sc = (idx < 32768) ? LOG2E : 1.0f;
    float4 v = *(const float4*)(s + (idx & 32767));
    us4 r = { f2bf(v.x * sc), f2bf(v.y * sc), f2bf(v.z * sc), f2bf(v.w * sc) };
    *(us4*)(wall + idx) = r;
}

// ---------------------------------------------------------------------------
// K1: MFMA projections (16x16 path, unchanged from R4 — verified correct).
//  tht/pht: [b][n][c] bf16 k-major; gg: [b][c][n] bf16 (k-major in j).
// ---------------------------------------------------------------------------
__global__ __launch_bounds__(512) void k_proj(
    const float* __restrict__ x, const u16* __restrict__ wall,
    const float* __restrict__ tb, const float* __restrict__ pb,
    const float* __restrict__ gbias,
    u16* __restrict__ tht, u16* __restrict__ pht, u16* __restrict__ gg)
{
    __shared__ u16 xs[64 * 264];    // x^T tile [n][c], pitch 264
    __shared__ u16 gbuf[128 * 68];  // g transpose bounce [o][n]
    const int tid = threadIdx.x;
    const int n0  = blockIdx.x * 64;
    const int b   = blockIdx.y;
    const int ln  = tid & 15, q = (tid >> 4) & 3, wid = tid >> 6;
    const int ow  = wid & 1, nw = wid >> 1;

    for (int p = 0; p < 8; ++p) {
        int id = p * 512 + tid;          // 4096 chunks: c(256) x n4(16)
        int c = id >> 4, n4 = (id & 15) * 4;
        float4 xv = *(const float4*)(x + ((size_t)b * CC + c) * NN + n0 + n4);
        xs[(n4 + 0) * 264 + c] = f2bf(xv.x);
        xs[(n4 + 1) * 264 + c] = f2bf(xv.y);
        xs[(n4 + 2) * 264 + c] = f2bf(xv.z);
        xs[(n4 + 3) * 264 + c] = f2bf(xv.w);
    }
    __syncthreads();

    short8 bfr[8];
    #pragma unroll
    for (int ks = 0; ks < 8; ++ks)
        bfr[ks] = *(const short8*)(&xs[(nw * 16 + ln) * 264 + ks * 32 + q * 8]);

    for (int pr = 0; pr < 3; ++pr) {
        const u16* wsrc = wall + pr * 32768;
        f32x4 acc[4];
        #pragma unroll
        for (int oo = 0; oo < 4; ++oo) acc[oo] = (f32x4){0.f, 0.f, 0.f, 0.f};
        for (int ks = 0; ks < 8; ++ks) {
            short8 a[4];
            #pragma unroll
            for (int oo = 0; oo < 4; ++oo)
                a[oo] = *(const short8*)(wsrc + (size_t)(ow*64 + oo*16 + ln) * 256 + ks*32 + q*8);
            #pragma unroll
            for (int oo = 0; oo < 4; ++oo)
                acc[oo] = MFMA16(a[oo], bfr[ks], acc[oo]);
        }
        const float* bias = (pr == 0) ? tb : (pr == 1 ? pb : gbias);
        const float bsc = (pr == 0) ? LOG2E : 1.0f;
        if (pr < 2) {
            u16* dst = (pr == 0) ? tht : pht;
            const int n = n0 + nw * 16 + ln;
            #pragma unroll
            for (int oo = 0; oo < 4; ++oo) {
                int o = ow * 64 + oo * 16 + q * 4;
                float4 bv = *(const float4*)(bias + o);
                f32x4 v = acc[oo];
                uint2 r = { pkbf(v.x + bv.x * bsc, v.y + bv.y * bsc),
                            pkbf(v.z + bv.z * bsc, v.w + bv.w * bsc) };
                *(uint2*)(dst + ((size_t)b * NN + n) * CHN + o) = r;
            }
        } else {
            const int nl = nw * 16 + ln;
            #pragma unroll
            for (int oo = 0; oo < 4; ++oo) {
                int o = ow * 64 + oo * 16 + q * 4;
                float4 bv = *(const float4*)(bias + o);
                f32x4 v = acc[oo];
                gbuf[(o + 0) * 68 + nl] = f2bf(v.x + bv.x);
                gbuf[(o + 1) * 68 + nl] = f2bf(v.y + bv.y);
                gbuf[(o + 2) * 68 + nl] = f2bf(v.z + bv.z);
                gbuf[(o + 3) * 68 + nl] = f2bf(v.w + bv.w);
            }
            __syncthreads();
            for (int p = 0; p < 4; ++p) {
                int id = p * 512 + tid;      // 2048 chunks: c(128) x n4(16)
                int c = id >> 4, n4 = (id & 15) * 4;
                us4 r = *(const us4*)(&gbuf[c * 68 + n4]);
                *(us4*)(gg + ((size_t)b * CHN + c) * NN + n0 + n4) = r;
            }
        }
    }
}

// ---------------------------------------------------------------------------
// K2: partial Z[b][j] += sum_i exp2(S2_ji), fp32 atomicAdd. 32x32x16 MFMA.
// 512 threads, grid (16 jb, 4 iq, B) = 256 blocks (1/CU, 2 waves/SIMD).
// j-tile 256 (wave owns one 32-j tile, theta frags in regs).
// i-range 1024 = 8 steps of 128, phi DOUBLE-BUFFERED (1 barrier/step).
// ---------------------------------------------------------------------------
__global__ __launch_bounds__(512, 2) void k_rowsum(
    const u16* __restrict__ tht, const u16* __restrict__ pht,
    float* __restrict__ Z)
{
    __shared__ u16 ph_s[2][128 * 128];   // 2 x 32 KB [i][c]
    const int tid = threadIdx.x;
    const int j0  = blockIdx.x * 256;
    const int i00 = blockIdx.y * 1024;
    const int b   = blockIdx.z;
    const int l   = tid & 63, w = tid >> 6;
    const int lm  = l & 31, lh = l >> 5;
    const u16* thb = tht + (size_t)b * NN * CHN;
    const u16* phb = pht + (size_t)b * NN * CHN;

    // theta A-frags (m = j): wave owns j-32 tile at j0 + w*32
    short8 ar[8];
    #pragma unroll
    for (int ks = 0; ks < 8; ++ks)
        ar[ks] = *(const short8*)(thb + (size_t)(j0 + w*32 + lm) * CHN + ks*16 + lh*8);

    // stage step 0
    for (int p = 0; p < 4; ++p) {
        int id = p * 512 + tid;
        int row = id >> 4, u = id & 15;
        short8 v = *(const short8*)(phb + (size_t)(i00 + row) * CHN + u * 8);
        *(short8*)(&ph_s[0][sw128(row, u)]) = v;
    }

    float zp[16];
    #pragma unroll
    for (int r = 0; r < 16; ++r) zp[r] = 0.f;

    for (int is = 0; is < 8; ++is) {
        __syncthreads();   // cur staged; other buffer's readers (step is-1) done
        if (is < 7) {
            for (int p = 0; p < 4; ++p) {
                int id = p * 512 + tid;
                int row = id >> 4, u = id & 15;
                short8 v = *(const short8*)(phb + (size_t)(i00 + (is+1)*128 + row) * CHN + u * 8);
                *(short8*)(&ph_s[(is + 1) & 1][sw128(row, u)]) = v;
            }
        }
        const u16* cur = ph_s[is & 1];

        #pragma unroll
        for (int ii = 0; ii < 4; ++ii) {
            f32x16 s;
            #pragma unroll
            for (int r = 0; r < 16; ++r) s[r] = 0.f;
            #pragma unroll
            for (int ks = 0; ks < 8; ++ks) {
                short8 bfrag = *(const short8*)(&cur[sw128(ii*32 + lm, ks*2 + lh)]);
                s = MFMA32(ar[ks], bfrag, s);
            }
            #pragma unroll
            for (int r = 0; r < 16; ++r) zp[r] += EXP2F(s[r]);
        }
    }

    // reduce over i (= lanes within each 32-half), then atomicAdd partial Z
    float zr[16];
    #pragma unroll
    for (int r = 0; r < 16; ++r) {
        float v = zp[r];
        v += __shfl_xor(v, 1);
        v += __shfl_xor(v, 2);
        v += __shfl_xor(v, 4);
        v += __shfl_xor(v, 8);
        v += __shfl_xor(v, 16);
        zr[r] = v;
    }
    if (lm == 0) {
        #pragma unroll
        for (int r = 0; r < 16; ++r) {
            int j = j0 + w*32 + (r & 3) + 8*(r >> 2) + 4*lh;
            atomicAdd(&Z[(size_t)b * NN + j], zr[r]);
        }
    }
}

// ---------------------------------------------------------------------------
// K3: fused attention, 512 threads, 32x32x16 MFMA, i-tile 256 (phi frags in
// regs), j-quarter 1024 = 8 steps of 128. Register-prefetch pipeline:
//   top:    issue global loads th/g(s+1) -> VGPRs
//   phase1: S2 = th.ph (A=th_s LDS, B=phr regs), C-init = -log2(Z)
//           -> E = exp2 -> E_s
//   sync1;  write th(s+1) regs -> LDS; phase2: pacc += g_s x E_s
//   sync2;  write g(s+1) regs -> LDS
// 2 barriers/step, staging latency hidden under phase1+phase2.
// LDS: th 32K + g 32K + E 64K = 128 KB; grid (16,4,B) = 256 blocks (1/CU).
// ---------------------------------------------------------------------------
__global__ __launch_bounds__(512, 2) void k_attn(
    const u16* __restrict__ tht, const u16* __restrict__ pht,
    const u16* __restrict__ gg, const float* __restrict__ Z,
    u16* __restrict__ innerT)
{
    __shared__ u16 th_s[128 * 128];   // [j][c]
    __shared__ u16 g_s [128 * 128];   // [c][j]
    __shared__ u16 E_s [256 * 128];   // [i][j]
    const int tid = threadIdx.x;
    const int i0  = blockIdx.x * 256;
    const int jq  = blockIdx.y;
    const int b   = blockIdx.z;
    const int l   = tid & 63, w = tid >> 6;
    const int lm  = l & 31, lh = l >> 5;
    const int h1  = w & 1;    // phase1 j-half / phase2 c-half (64)
    const int h2  = w >> 1;   // i-group (4 groups of 64)

    const u16*  thb = tht + (size_t)b * NN * CHN;
    const u16*  ggb = gg  + (size_t)b * CHN * NN;
    const float* Zb = Z   + (size_t)b * NN;

    // staging chunk mapping (shared by th and g tiles: 128 rows x 16 chunks)
    int srow[4], su[4];
    #pragma unroll
    for (int p = 0; p < 4; ++p) {
        int id = p * 512 + tid;
        srow[p] = id >> 4; su[p] = id & 15;
    }

    // phi B-frags (n = i): wave owns i-64 (2 tiles of 32), registers
    short8 phr[2][8];
    #pragma unroll
    for (int ii = 0; ii < 2; ++ii)
        #pragma unroll
        for (int ks = 0; ks < 8; ++ks)
            phr[ii][ks] = *(const short8*)(pht + ((size_t)b * NN + i0 + h2*64 + ii*32 + lm) * CHN + ks*16 + lh*8);

    // prologue: stage th/g for step 0
    #pragma unroll
    for (int p = 0; p < 4; ++p) {
        short8 tv = *(const short8*)(thb + (size_t)(jq*1024 + srow[p]) * CHN + su[p] * 8);
        short8 gv = *(const short8*)(ggb + (size_t)srow[p] * NN + jq*1024 + su[p] * 8);
        *(short8*)(&th_s[sw128(srow[p], su[p])]) = tv;
        *(short8*)(&g_s [sw128(srow[p], su[p])]) = gv;
    }
    __syncthreads();

    f32x16 pacc[2][2];   // [cc][ii]
    #pragma unroll
    for (int cc = 0; cc < 2; ++cc)
        #pragma unroll
        for (int ii = 0; ii < 2; ++ii)
            #pragma unroll
            for (int r = 0; r < 16; ++r) pacc[cc][ii][r] = 0.f;

    for (int s = 0; s < 8; ++s) {
        const int j0 = jq * 1024 + s * 128;

        // prefetch next step's th/g into registers (consumed after the syncs)
        short8 thn[4], gn[4];
        if (s < 7) {
            const int jn = j0 + 128;
            #pragma unroll
            for (int p = 0; p < 4; ++p) {
                thn[p] = *(const short8*)(thb + (size_t)(jn + srow[p]) * CHN + su[p] * 8);
                gn[p]  = *(const short8*)(ggb + (size_t)srow[p] * NN + jn + su[p] * 8);
            }
        }

        // ---- phase 1: per j-32 tile, S2 with C-init=-log2(Z), exp2 -> E_s
        #pragma unroll
        for (int jj = 0; jj < 2; ++jj) {
            const int jbase = h1*64 + jj*32;
            f32x16 cinit;
            #pragma unroll
            for (int rq = 0; rq < 4; ++rq) {
                float4 Lv = *(const float4*)(Zb + j0 + jbase + rq*8 + lh*4);
                cinit[rq*4 + 0] = -LOG2F(Lv.x);
                cinit[rq*4 + 1] = -LOG2F(Lv.y);
                cinit[rq*4 + 2] = -LOG2F(Lv.z);
                cinit[rq*4 + 3] = -LOG2F(Lv.w);
            }
            f32x16 s0 = cinit, s1 = cinit;
            #pragma unroll
            for (int ks = 0; ks < 8; ++ks) {
                short8 a = *(const short8*)(&th_s[sw128(jbase + lm, ks*2 + lh)]);
                s0 = MFMA32(a, phr[0][ks], s0);
                s1 = MFMA32(a, phr[1][ks], s1);
            }
            #pragma unroll
            for (int ii = 0; ii < 2; ++ii) {
                const f32x16 sv = ii ? s1 : s0;
                const int ri = h2*64 + ii*32 + lm;
                #pragma unroll
                for (int rq = 0; rq < 4; ++rq) {
                    const int jl = jbase + rq*8 + lh*4;
                    uint2 e = { pkbf(EXP2F(sv[rq*4+0]), EXP2F(sv[rq*4+1])),
                                pkbf(EXP2F(sv[rq*4+2]), EXP2F(sv[rq*4+3])) };
                    *(uint2*)(&E_s[ri*128 + (((jl >> 3) ^ (ri & 7)) << 3) + (jl & 7)]) = e;
                }
            }
        }
        __syncthreads();   // E ready; th_s consumed

        if (s < 7) {
            #pragma unroll
            for (int p = 0; p < 4; ++p)
                *(short8*)(&th_s[sw128(srow[p], su[p])]) = thn[p];
        }

        // ---- phase 2: pacc[c][i] += g x E
        #pragma unroll
        for (int ks = 0; ks < 8; ++ks) {
            short8 eb[2];
            #pragma unroll
            for (int ii = 0; ii < 2; ++ii)
                eb[ii] = *(const short8*)(&E_s[sw128(h2*64 + ii*32 + lm, ks*2 + lh)]);
            #pragma unroll
            for (int cc = 0; cc < 2; ++cc) {
                short8 ag = *(const short8*)(&g_s[sw128(h1*64 + cc*32 + lm, ks*2 + lh)]);
                pacc[cc][0] = MFMA32(ag, eb[0], pacc[cc][0]);
                pacc[cc][1] = MFMA32(ag, eb[1], pacc[cc][1]);
            }
        }
        __syncthreads();   // g_s and E_s consumed

        if (s < 7) {
            #pragma unroll
            for (int p = 0; p < 4; ++p)
                *(short8*)(&g_s[sw128(srow[p], su[p])]) = gn[p];
        }
    }

    // epilogue: D col=i (lane), rows = c (quad groups of 4) -> 8B stores [i][c]
    u16* dst = innerT + ((size_t)jq * BB + b) * (size_t)NN * CHN;
    #pragma unroll
    for (int cc = 0; cc < 2; ++cc)
        #pragma unroll
        for (int ii = 0; ii < 2; ++ii) {
            const int i = i0 + h2*64 + ii*32 + lm;
            const f32x16 v = pacc[cc][ii];
            #pragma unroll
            for (int rq = 0; rq < 4; ++rq) {
                const int c0 = h1*64 + cc*32 + rq*8 + lh*4;
                uint2 r = { pkbf(v[rq*4+0], v[rq*4+1]),
                            pkbf(v[rq*4+2], v[rq*4+3]) };
                *(uint2*)(dst + (size_t)i * CHN + c0) = r;
            }
        }
}

// ---------------------------------------------------------------------------
// K4: out[b][o][n] = Wb[o] + x[b][o][n] + sum_c Ww[o][c]*(sum_q innerT_q)[n][c]
// 32x32 MFMA; Ww staged in LDS once (A-frags hoisted to regs); innerT tiles
// staged per quarter. D col = n -> fully coalesced scalar stores + x residual.
// LDS 80 KB. Grid (64 nb, B) = 256 blocks, 512 threads.
// ---------------------------------------------------------------------------
__global__ __launch_bounds__(512, 2) void k_final(
    const u16* __restrict__ innerT, const float* __restrict__ x,
    const u16* __restrict__ Wwbf, const float* __restrict__ Wb,
    float* __restrict__ out)
{
    __shared__ u16 w_s[256 * 128];   // 64 KB [o][c]
    __shared__ u16 a_s[64 * 128];    // 16 KB [n][c]
    const int tid = threadIdx.x;
    const int n0  = blockIdx.x * 64;
    const int b   = blockIdx.y;
    const int l   = tid & 63, w = tid >> 6;
    const int lm  = l & 31, lh = l >> 5;

    // stage Ww (coalesced; k-major rows)
    for (int p = 0; p < 8; ++p) {
        int id = p * 512 + tid;
        int row = id >> 4, u = id & 15;
        *(short8*)(&w_s[sw128(row, u)]) = *(const short8*)(Wwbf + (size_t)row * CHN + u * 8);
    }
    __syncthreads();

    // A-frags (m = o): wave owns o-32 at w*32
    short8 aw[8];
    #pragma unroll
    for (int ks = 0; ks < 8; ++ks)
        aw[ks] = *(const short8*)(&w_s[sw128(w*32 + lm, ks*2 + lh)]);

    f32x16 acc[2];
    #pragma unroll
    for (int nt = 0; nt < 2; ++nt)
        #pragma unroll
        for (int r = 0; r < 16; ++r) acc[nt][r] = 0.f;

    for (int jq = 0; jq < 4; ++jq) {
        __syncthreads();   // a_s free
        for (int p = 0; p < 2; ++p) {
            int id = p * 512 + tid;
            int row = id >> 4, u = id & 15;
            *(short8*)(&a_s[sw128(row, u)]) =
                *(const short8*)(innerT + (((size_t)jq * BB + b) * NN + n0 + row) * CHN + u * 8);
        }
        __syncthreads();
        #pragma unroll
        for (int ks = 0; ks < 8; ++ks) {
            short8 bn[2];
            #pragma unroll
            for (int nt = 0; nt < 2; ++nt)
                bn[nt] = *(const short8*)(&a_s[sw128(nt*32 + lm, ks*2 + lh)]);
            acc[0] = MFMA32(aw[ks], bn[0], acc[0]);
            acc[1] = MFMA32(aw[ks], bn[1], acc[1]);
        }
    }

    // epilogue: D col = n (lane), row = o; coalesced 4B stores + bias + x
    #pragma unroll
    for (int nt = 0; nt < 2; ++nt) {
        const int n = n0 + nt*32 + lm;
        #pragma unroll
        for (int r = 0; r < 16; ++r) {
            const int o = w*32 + (r & 3) + 8*(r >> 2) + 4*lh;
            const size_t idx = ((size_t)b * CC + o) * NN + n;
            out[idx] = acc[nt][r] + Wb[o] + x[idx];
        }
    }
}

// ---------------------------------------------------------------------------
extern "C" void kernel_launch(void* const* d_in, const int* in_sizes, int n_in,
                              void* d_out, int out_size, void* d_ws, size_t ws_size,
                              hipStream_t stream)
{
    const float* x  = (const float*)d_in[0];
    const float* tw = (const float*)d_in[1];
    const float* tb = (const float*)d_in[2];
    const float* pw = (const float*)d_in[3];
    const float* pb = (const float*)d_in[4];
    const float* gw = (const float*)d_in[5];
    const float* gb = (const float*)d_in[6];
    const float* Ww = (const float*)d_in[7];
    const float* Wb = (const float*)d_in[8];
    float* out = (float*)d_out;

    // Workspace (~29 MB): tht|pht|gg (4MB ea bf16) | wall (256KB) |
    // Z (64KB fp32, memset to 0) | innerT 4 quarters x 4MB bf16.
    char* p = (char*)d_ws;
    const size_t proj_u16 = (size_t)BB * NN * CHN;   // 2,097,152
    u16*   tht    = (u16*)p;   p += proj_u16 * 2;
    u16*   pht    = (u16*)p;   p += proj_u16 * 2;
    u16*   gg     = (u16*)p;   p += proj_u16 * 2;
    u16*   wall   = (u16*)p;   p += (size_t)131072 * 2;
    float* Z      = (float*)p; p += (size_t)BB * NN * 4;
    u16*   innerT = (u16*)p;

    hipMemsetAsync(Z, 0, (size_t)BB * NN * sizeof(float), stream);
    k_cvtw  <<<128, 256, 0, stream>>>(tw, pw, gw, Ww, wall);
    k_proj  <<<dim3(64, BB), 512, 0, stream>>>(x, wall, tb, pb, gb, tht, pht, gg);
    k_rowsum<<<dim3(16, 4, BB), 512, 0, stream>>>(tht, pht, Z);
    k_attn  <<<dim3(16, 4, BB), 512, 0, stream>>>(tht, pht, gg, Z, innerT);
    k_final <<<dim3(64, BB), 512, 0, stream>>>(innerT, x, wall + 98304, Wb, out);
}

// Round 7
// 191.784 us; speedup vs baseline: 1.2797x; 1.0243x over previous
//
#include <hip/hip_runtime.h>
#include <hip/hip_bf16.h>
#include <math.h>

// Problem constants (fixed by the reference).
#define BB    4
#define CC    256
#define CHN   128
#define NN    4096

typedef short short8 __attribute__((ext_vector_type(8)));    // 8 bf16 (MFMA A/B frag)
typedef float f32x4  __attribute__((ext_vector_type(4)));    // 16x16 C/D frag
typedef float f32x16 __attribute__((ext_vector_type(16)));   // 32x32 C/D frag
typedef unsigned short u16;
typedef u16  us4 __attribute__((ext_vector_type(4)));

#define MFMA16(a, b, c) __builtin_amdgcn_mfma_f32_16x16x32_bf16((a), (b), (c), 0, 0, 0)
#define MFMA32(a, b, c) __builtin_amdgcn_mfma_f32_32x32x16_bf16((a), (b), (c), 0, 0, 0)
#define LOG2E 1.4426950408889634f

#if __has_builtin(__builtin_amdgcn_exp2f)
#define EXP2F(x) __builtin_amdgcn_exp2f(x)
#else
#define EXP2F(x) exp2f(x)
#endif
#if __has_builtin(__builtin_amdgcn_logf)
#define LOG2F(x) __builtin_amdgcn_logf(x)   // v_log_f32 IS log2
#else
#define LOG2F(x) log2f(x)
#endif

static __device__ __forceinline__ u16 f2bf(float f) {           // RNE float->bf16
    union { float f; unsigned u; } v; v.f = f;
    unsigned r = v.u + 0x7FFFu + ((v.u >> 16) & 1u);
    return (u16)(r >> 16);
}
// packed f32x2 -> bf16x2 (v_cvt_pk_bf16_f32 on gfx950)
static __device__ __forceinline__ unsigned pkbf(float a, float b) {
    __hip_bfloat162 h = __float22bfloat162_rn(make_float2(a, b));
    return *reinterpret_cast<unsigned*>(&h);
}
// XOR-swizzled LDS address (u16 units), [row][128] bf16 tiles, 16B chunks.
static __device__ __forceinline__ int sw128(int row, int u) {
    return row * 128 + ((u ^ (row & 7)) << 3);
}

// ---------------------------------------------------------------------------
// K0: convert 4 weight matrices fp32->bf16. wall = [tw|pw|gw|Ww], 32768 each.
// theta weights pre-scaled by log2(e): scores land in exp2 domain.
// ---------------------------------------------------------------------------
__global__ __launch_bounds__(256) void k_cvtw(
    const float* __restrict__ tw, const float* __restrict__ pw,
    const float* __restrict__ gw, const float* __restrict__ Ww,
    u16* __restrict__ wall)
{
    int idx = (blockIdx.x * 256 + threadIdx.x) * 4;   // 0 .. 131071
    const float* s = (idx < 32768) ? tw
                   : (idx < 65536) ? pw
                   : (idx < 98304) ? gw : Ww;
    float sc = (idx < 32768) ? LOG2E : 1.0f;
    float4 v = *(const float4*)(s + (idx & 32767));
    us4 r = { f2bf(v.x * sc), f2bf(v.y * sc), f2bf(v.z * sc), f2bf(v.w * sc) };
    *(us4*)(wall + idx) = r;
}

// ---------------------------------------------------------------------------
// K1: MFMA projections (16x16 path, unchanged — validated R4/R6).
//  tht/pht: [b][n][c] bf16 k-major; gg: [b][c][n] bf16 (k-major in j).
// ---------------------------------------------------------------------------
__global__ __launch_bounds__(512) void k_proj(
    const float* __restrict__ x, const u16* __restrict__ wall,
    const float* __restrict__ tb, const float* __restrict__ pb,
    const float* __restrict__ gbias,
    u16* __restrict__ tht, u16* __restrict__ pht, u16* __restrict__ gg)
{
    __shared__ u16 xs[64 * 264];    // x^T tile [n][c], pitch 264
    __shared__ u16 gbuf[128 * 68];  // g transpose bounce [o][n]
    const int tid = threadIdx.x;
    const int n0  = blockIdx.x * 64;
    const int b   = blockIdx.y;
    const int ln  = tid & 15, q = (tid >> 4) & 3, wid = tid >> 6;
    const int ow  = wid & 1, nw = wid >> 1;

    for (int p = 0; p < 8; ++p) {
        int id = p * 512 + tid;          // 4096 chunks: c(256) x n4(16)
        int c = id >> 4, n4 = (id & 15) * 4;
        float4 xv = *(const float4*)(x + ((size_t)b * CC + c) * NN + n0 + n4);
        xs[(n4 + 0) * 264 + c] = f2bf(xv.x);
        xs[(n4 + 1) * 264 + c] = f2bf(xv.y);
        xs[(n4 + 2) * 264 + c] = f2bf(xv.z);
        xs[(n4 + 3) * 264 + c] = f2bf(xv.w);
    }
    __syncthreads();

    short8 bfr[8];
    #pragma unroll
    for (int ks = 0; ks < 8; ++ks)
        bfr[ks] = *(const short8*)(&xs[(nw * 16 + ln) * 264 + ks * 32 + q * 8]);

    for (int pr = 0; pr < 3; ++pr) {
        const u16* wsrc = wall + pr * 32768;
        f32x4 acc[4];
        #pragma unroll
        for (int oo = 0; oo < 4; ++oo) acc[oo] = (f32x4){0.f, 0.f, 0.f, 0.f};
        for (int ks = 0; ks < 8; ++ks) {
            short8 a[4];
            #pragma unroll
            for (int oo = 0; oo < 4; ++oo)
                a[oo] = *(const short8*)(wsrc + (size_t)(ow*64 + oo*16 + ln) * 256 + ks*32 + q*8);
            #pragma unroll
            for (int oo = 0; oo < 4; ++oo)
                acc[oo] = MFMA16(a[oo], bfr[ks], acc[oo]);
        }
        const float* bias = (pr == 0) ? tb : (pr == 1 ? pb : gbias);
        const float bsc = (pr == 0) ? LOG2E : 1.0f;
        if (pr < 2) {
            u16* dst = (pr == 0) ? tht : pht;
            const int n = n0 + nw * 16 + ln;
            #pragma unroll
            for (int oo = 0; oo < 4; ++oo) {
                int o = ow * 64 + oo * 16 + q * 4;
                float4 bv = *(const float4*)(bias + o);
                f32x4 v = acc[oo];
                uint2 r = { pkbf(v.x + bv.x * bsc, v.y + bv.y * bsc),
                            pkbf(v.z + bv.z * bsc, v.w + bv.w * bsc) };
                *(uint2*)(dst + ((size_t)b * NN + n) * CHN + o) = r;
            }
        } else {
            const int nl = nw * 16 + ln;
            #pragma unroll
            for (int oo = 0; oo < 4; ++oo) {
                int o = ow * 64 + oo * 16 + q * 4;
                float4 bv = *(const float4*)(bias + o);
                f32x4 v = acc[oo];
                gbuf[(o + 0) * 68 + nl] = f2bf(v.x + bv.x);
                gbuf[(o + 1) * 68 + nl] = f2bf(v.y + bv.y);
                gbuf[(o + 2) * 68 + nl] = f2bf(v.z + bv.z);
                gbuf[(o + 3) * 68 + nl] = f2bf(v.w + bv.w);
            }
            __syncthreads();
            for (int p = 0; p < 4; ++p) {
                int id = p * 512 + tid;      // 2048 chunks: c(128) x n4(16)
                int c = id >> 4, n4 = (id & 15) * 4;
                us4 r = *(const us4*)(&gbuf[c * 68 + n4]);
                *(us4*)(gg + ((size_t)b * CHN + c) * NN + n0 + n4) = r;
            }
        }
    }
}

// ---------------------------------------------------------------------------
// K2: partial Z[b][j] += sum_i exp2(S2_ji), fp32 atomicAdd. 32x32x16 MFMA.
// Unchanged from R6 (validated).
// ---------------------------------------------------------------------------
__global__ __launch_bounds__(512, 2) void k_rowsum(
    const u16* __restrict__ tht, const u16* __restrict__ pht,
    float* __restrict__ Z)
{
    __shared__ u16 ph_s[2][128 * 128];   // 2 x 32 KB [i][c]
    const int tid = threadIdx.x;
    const int j0  = blockIdx.x * 256;
    const int i00 = blockIdx.y * 1024;
    const int b   = blockIdx.z;
    const int l   = tid & 63, w = tid >> 6;
    const int lm  = l & 31, lh = l >> 5;
    const u16* thb = tht + (size_t)b * NN * CHN;
    const u16* phb = pht + (size_t)b * NN * CHN;

    short8 ar[8];
    #pragma unroll
    for (int ks = 0; ks < 8; ++ks)
        ar[ks] = *(const short8*)(thb + (size_t)(j0 + w*32 + lm) * CHN + ks*16 + lh*8);

    for (int p = 0; p < 4; ++p) {
        int id = p * 512 + tid;
        int row = id >> 4, u = id & 15;
        short8 v = *(const short8*)(phb + (size_t)(i00 + row) * CHN + u * 8);
        *(short8*)(&ph_s[0][sw128(row, u)]) = v;
    }

    float zp[16];
    #pragma unroll
    for (int r = 0; r < 16; ++r) zp[r] = 0.f;

    for (int is = 0; is < 8; ++is) {
        __syncthreads();
        if (is < 7) {
            for (int p = 0; p < 4; ++p) {
                int id = p * 512 + tid;
                int row = id >> 4, u = id & 15;
                short8 v = *(const short8*)(phb + (size_t)(i00 + (is+1)*128 + row) * CHN + u * 8);
                *(short8*)(&ph_s[(is + 1) & 1][sw128(row, u)]) = v;
            }
        }
        const u16* cur = ph_s[is & 1];

        #pragma unroll
        for (int ii = 0; ii < 4; ++ii) {
            f32x16 s;
            #pragma unroll
            for (int r = 0; r < 16; ++r) s[r] = 0.f;
            #pragma unroll
            for (int ks = 0; ks < 8; ++ks) {
                short8 bfrag = *(const short8*)(&cur[sw128(ii*32 + lm, ks*2 + lh)]);
                s = MFMA32(ar[ks], bfrag, s);
            }
            #pragma unroll
            for (int r = 0; r < 16; ++r) zp[r] += EXP2F(s[r]);
        }
    }

    float zr[16];
    #pragma unroll
    for (int r = 0; r < 16; ++r) {
        float v = zp[r];
        v += __shfl_xor(v, 1);
        v += __shfl_xor(v, 2);
        v += __shfl_xor(v, 4);
        v += __shfl_xor(v, 8);
        v += __shfl_xor(v, 16);
        zr[r] = v;
    }
    if (lm == 0) {
        #pragma unroll
        for (int r = 0; r < 16; ++r) {
            int j = j0 + w*32 + (r & 3) + 8*(r >> 2) + 4*lh;
            atomicAdd(&Z[(size_t)b * NN + j], zr[r]);
        }
    }
}

// ---------------------------------------------------------------------------
// K2b: L[j] = -log2(Z[j])  (negated log-partition; k_attn C-init reads this)
// ---------------------------------------------------------------------------
__global__ __launch_bounds__(256) void k_log(
    const float* __restrict__ Z, float* __restrict__ L)
{
    int idx = (blockIdx.x * 256 + threadIdx.x) * 4;
    float4 z = *(const float4*)(Z + idx);
    float4 r = { -LOG2F(z.x), -LOG2F(z.y), -LOG2F(z.z), -LOG2F(z.w) };
    *(float4*)(L + idx) = r;
}

// ---------------------------------------------------------------------------
// K3: fused attention — BARRIER-MINIMAL (1 __syncthreads per j-step).
// 512 threads, 32x32x16. Each wave owns an i-32 column group (8 waves = i-256
// block tile); phi B-frags in registers. Per step (j-128, dbuf th/g in LDS):
//   for each j-32 tile: S D-frag = MFMA(theta_LDS, phi_regs) with C-init=L_j
//     -> E = exp2 in REGISTERS -> repack D->B-operand via __shfl_xor(.,32)
//     -> PV: pacc[c][i-32] += MFMA(g_LDS, E_regs)
// E never touches LDS; no inter-wave dependency inside a step.
// LDS: th 2x32K + g 2x32K = 128 KB. Grid (16,4,B) = 256 blocks (1/CU).
// D-layout (m74/m101): col=lane&31, row=(r&3)+8*(r>>2)+4*(lane>>5).
// A/B-frag: lane=m(or n), k = chunk*8.. (validated by R6 pass).
// ---------------------------------------------------------------------------
__global__ __launch_bounds__(512, 2) void k_attn(
    const u16* __restrict__ tht, const u16* __restrict__ pht,
    const u16* __restrict__ gg, const float* __restrict__ Lbuf,
    u16* __restrict__ innerT)
{
    __shared__ u16 th_s[2][128 * 128];   // [j][c] per step, dbuf
    __shared__ u16 g_s [2][128 * 128];   // [c][j] per step, dbuf
    const int tid = threadIdx.x;
    const int i0  = blockIdx.x * 256;
    const int jq  = blockIdx.y;
    const int b   = blockIdx.z;
    const int w   = tid >> 6;
    const int lm  = tid & 31, lh = (tid >> 5) & 1;

    const u16*  thb = tht + (size_t)b * NN * CHN;
    const u16*  ggb = gg  + (size_t)b * CHN * NN;
    const float* Lb = Lbuf + (size_t)b * NN;

    int srow[4], su[4];
    #pragma unroll
    for (int p = 0; p < 4; ++p) {
        int id = p * 512 + tid;
        srow[p] = id >> 4; su[p] = id & 15;
    }

    // phi B-frags for this wave's i-32 (col n = lm), all K=128: registers.
    short8 phr[8];
    #pragma unroll
    for (int ks = 0; ks < 8; ++ks)
        phr[ks] = *(const short8*)(pht + ((size_t)b * NN + i0 + w*32 + lm) * CHN + ks*16 + lh*8);

    // prologue: stage step 0 into buffer 0
    #pragma unroll
    for (int p = 0; p < 4; ++p) {
        short8 tv = *(const short8*)(thb + (size_t)(jq*1024 + srow[p]) * CHN + su[p] * 8);
        short8 gv = *(const short8*)(ggb + (size_t)srow[p] * NN + jq*1024 + su[p] * 8);
        *(short8*)(&th_s[0][sw128(srow[p], su[p])]) = tv;
        *(short8*)(&g_s [0][sw128(srow[p], su[p])]) = gv;
    }
    __syncthreads();

    f32x16 pacc[4];   // [c-tile]: rows c, col i = lm (wave's i-32)
    #pragma unroll
    for (int ct = 0; ct < 4; ++ct)
        #pragma unroll
        for (int r = 0; r < 16; ++r) pacc[ct][r] = 0.f;

    for (int s = 0; s < 8; ++s) {
        const int j0s = jq * 1024 + s * 128;
        const u16* thc = th_s[s & 1];
        const u16* gc  = g_s [s & 1];

        // prefetch next step's th/g into registers (written to LDS pre-barrier)
        short8 thn[4], gn[4];
        if (s < 7) {
            #pragma unroll
            for (int p = 0; p < 4; ++p) {
                thn[p] = *(const short8*)(thb + (size_t)(j0s + 128 + srow[p]) * CHN + su[p] * 8);
                gn[p]  = *(const short8*)(ggb + (size_t)srow[p] * NN + j0s + 128 + su[p] * 8);
            }
        }

        #pragma unroll
        for (int jj = 0; jj < 4; ++jj) {
            // --- S-tile: C-init = -log2 Z (precomputed), rows j, col i=lm
            f32x16 sv;
            #pragma unroll
            for (int rq = 0; rq < 4; ++rq) {
                float4 Lv = *(const float4*)(Lb + j0s + jj*32 + rq*8 + lh*4);
                sv[rq*4 + 0] = Lv.x; sv[rq*4 + 1] = Lv.y;
                sv[rq*4 + 2] = Lv.z; sv[rq*4 + 3] = Lv.w;
            }
            #pragma unroll
            for (int ks = 0; ks < 8; ++ks) {
                short8 a = *(const short8*)(&thc[sw128(jj*32 + lm, ks*2 + lh)]);
                sv = MFMA32(a, phr[ks], sv);
            }
            // --- E = exp2(sv), packed bf16x2; reg p holds j-pair J(p)+4*lh,
            //     J = [0,2,8,10,16,18,24,26]
            unsigned e0 = pkbf(EXP2F(sv[0]),  EXP2F(sv[1]));
            unsigned e1 = pkbf(EXP2F(sv[2]),  EXP2F(sv[3]));
            unsigned e2 = pkbf(EXP2F(sv[4]),  EXP2F(sv[5]));
            unsigned e3 = pkbf(EXP2F(sv[6]),  EXP2F(sv[7]));
            unsigned e4 = pkbf(EXP2F(sv[8]),  EXP2F(sv[9]));
            unsigned e5 = pkbf(EXP2F(sv[10]), EXP2F(sv[11]));
            unsigned e6 = pkbf(EXP2F(sv[12]), EXP2F(sv[13]));
            unsigned e7 = pkbf(EXP2F(sv[14]), EXP2F(sv[15]));
            // --- partner half (lane ^ 32): same j-pairs with lh flipped
            unsigned s0 = __shfl_xor(e0, 32), s1 = __shfl_xor(e1, 32);
            unsigned s2 = __shfl_xor(e2, 32), s3 = __shfl_xor(e3, 32);
            unsigned s4 = __shfl_xor(e4, 32), s5 = __shfl_xor(e5, 32);
            unsigned s6 = __shfl_xor(e6, 32), s7 = __shfl_xor(e7, 32);
            // --- assemble B-operand frags (k = j contiguous-8 per lane-half)
            union { unsigned u[4]; short8 v; } f[2];
            f[0].u[0] = lh ? s2 : e0;  f[0].u[1] = lh ? s3 : e1;
            f[0].u[2] = lh ? e2 : s0;  f[0].u[3] = lh ? e3 : s1;
            f[1].u[0] = lh ? s6 : e4;  f[1].u[1] = lh ? s7 : e5;
            f[1].u[2] = lh ? e6 : s4;  f[1].u[3] = lh ? e7 : s5;
            // --- PV: pacc[c][i] += g[c][j] x E[j][i]  (K = this jj's 32 j)
            #pragma unroll
            for (int h = 0; h < 2; ++h) {
                #pragma unroll
                for (int ct = 0; ct < 4; ++ct) {
                    short8 ag = *(const short8*)(&gc[sw128(ct*32 + lm, jj*4 + h*2 + lh)]);
                    pacc[ct] = MFMA32(ag, f[h].v, pacc[ct]);
                }
            }
        }

        if (s < 7) {
            const int nb = (s + 1) & 1;
            #pragma unroll
            for (int p = 0; p < 4; ++p) {
                *(short8*)(&th_s[nb][sw128(srow[p], su[p])]) = thn[p];
                *(short8*)(&g_s [nb][sw128(srow[p], su[p])]) = gn[p];
            }
        }
        __syncthreads();   // the ONLY barrier per step
    }

    // epilogue: D col = i (lane), rows = c -> 8B stores into innerT[i][c]
    u16* dst = innerT + ((size_t)jq * BB + b) * (size_t)NN * CHN;
    const int i = i0 + w*32 + lm;
    #pragma unroll
    for (int ct = 0; ct < 4; ++ct) {
        #pragma unroll
        for (int rq = 0; rq < 4; ++rq) {
            const int c0 = ct*32 + rq*8 + lh*4;
            uint2 r = { pkbf(pacc[ct][rq*4+0], pacc[ct][rq*4+1]),
                        pkbf(pacc[ct][rq*4+2], pacc[ct][rq*4+3]) };
            *(uint2*)(dst + (size_t)i * CHN + c0) = r;
        }
    }
}

// ---------------------------------------------------------------------------
// K4: out = Wb + x + Ww.(sum_q innerT_q)  — unchanged from R6 (validated).
// ---------------------------------------------------------------------------
__global__ __launch_bounds__(512, 2) void k_final(
    const u16* __restrict__ innerT, const float* __restrict__ x,
    const u16* __restrict__ Wwbf, const float* __restrict__ Wb,
    float* __restrict__ out)
{
    __shared__ u16 w_s[256 * 128];   // 64 KB [o][c]
    __shared__ u16 a_s[64 * 128];    // 16 KB [n][c]
    const int tid = threadIdx.x;
    const int n0  = blockIdx.x * 64;
    const int b   = blockIdx.y;
    const int l   = tid & 63, w = tid >> 6;
    const int lm  = l & 31, lh = l >> 5;

    for (int p = 0; p < 8; ++p) {
        int id = p * 512 + tid;
        int row = id >> 4, u = id & 15;
        *(short8*)(&w_s[sw128(row, u)]) = *(const short8*)(Wwbf + (size_t)row * CHN + u * 8);
    }
    __syncthreads();

    short8 aw[8];
    #pragma unroll
    for (int ks = 0; ks < 8; ++ks)
        aw[ks] = *(const short8*)(&w_s[sw128(w*32 + lm, ks*2 + lh)]);

    f32x16 acc[2];
    #pragma unroll
    for (int nt = 0; nt < 2; ++nt)
        #pragma unroll
        for (int r = 0; r < 16; ++r) acc[nt][r] = 0.f;

    for (int jq = 0; jq < 4; ++jq) {
        __syncthreads();
        for (int p = 0; p < 2; ++p) {
            int id = p * 512 + tid;
            int row = id >> 4, u = id & 15;
            *(short8*)(&a_s[sw128(row, u)]) =
                *(const short8*)(innerT + (((size_t)jq * BB + b) * NN + n0 + row) * CHN + u * 8);
        }
        __syncthreads();
        #pragma unroll
        for (int ks = 0; ks < 8; ++ks) {
            short8 bn[2];
            #pragma unroll
            for (int nt = 0; nt < 2; ++nt)
                bn[nt] = *(const short8*)(&a_s[sw128(nt*32 + lm, ks*2 + lh)]);
            acc[0] = MFMA32(aw[ks], bn[0], acc[0]);
            acc[1] = MFMA32(aw[ks], bn[1], acc[1]);
        }
    }

    #pragma unroll
    for (int nt = 0; nt < 2; ++nt) {
        const int n = n0 + nt*32 + lm;
        #pragma unroll
        for (int r = 0; r < 16; ++r) {
            const int o = w*32 + (r & 3) + 8*(r >> 2) + 4*lh;
            const size_t idx = ((size_t)b * CC + o) * NN + n;
            out[idx] = acc[nt][r] + Wb[o] + x[idx];
        }
    }
}

// ---------------------------------------------------------------------------
extern "C" void kernel_launch(void* const* d_in, const int* in_sizes, int n_in,
                              void* d_out, int out_size, void* d_ws, size_t ws_size,
                              hipStream_t stream)
{
    const float* x  = (const float*)d_in[0];
    const float* tw = (const float*)d_in[1];
    const float* tb = (const float*)d_in[2];
    const float* pw = (const float*)d_in[3];
    const float* pb = (const float*)d_in[4];
    const float* gw = (const float*)d_in[5];
    const float* gb = (const float*)d_in[6];
    const float* Ww = (const float*)d_in[7];
    const float* Wb = (const float*)d_in[8];
    float* out = (float*)d_out;

    // Workspace (~29 MB): tht|pht|gg (4MB ea bf16) | wall (256KB) |
    // Z (64KB, memset 0) | L (64KB) | innerT 4 quarters x 4MB bf16.
    char* p = (char*)d_ws;
    const size_t proj_u16 = (size_t)BB * NN * CHN;   // 2,097,152
    u16*   tht    = (u16*)p;   p += proj_u16 * 2;
    u16*   pht    = (u16*)p;   p += proj_u16 * 2;
    u16*   gg     = (u16*)p;   p += proj_u16 * 2;
    u16*   wall   = (u16*)p;   p += (size_t)131072 * 2;
    float* Z      = (float*)p; p += (size_t)BB * NN * 4;
    float* Lbuf   = (float*)p; p += (size_t)BB * NN * 4;
    u16*   innerT = (u16*)p;

    hipMemsetAsync(Z, 0, (size_t)BB * NN * sizeof(float), stream);
    k_cvtw  <<<128, 256, 0, stream>>>(tw, pw, gw, Ww, wall);
    k_proj  <<<dim3(64, BB), 512, 0, stream>>>(x, wall, tb, pb, gb, tht, pht, gg);
    k_rowsum<<<dim3(16, 4, BB), 512, 0, stream>>>(tht, pht, Z);
    k_log   <<<16, 256, 0, stream>>>(Z, Lbuf);
    k_attn  <<<dim3(16, 4, BB), 512, 0, stream>>>(tht, pht, gg, Lbuf, innerT);
    k_final <<<dim3(64, BB), 512, 0, stream>>>(innerT, x, wall + 98304, Wb, out);
}